// Round 8
// baseline (210.313 us; speedup 1.0000x reference)
//
#include <hip/hip_runtime.h>
#include <stdint.h>

#define N_NODES 100000
#define F_DIM   500
#define C_DIM   40
#define H_DIM   256
#define HX_DIM  64
#define O_DIM   320   // H + HX
#define E_NUM   1600000

typedef unsigned short u16;
typedef unsigned int   u32;
typedef __attribute__((ext_vector_type(4))) u16    u16x4;
typedef __attribute__((ext_vector_type(8))) u16    u16x8;
typedef __attribute__((ext_vector_type(4))) float  f32x4;
typedef __attribute__((ext_vector_type(8))) short  bf16x8;  // MFMA A/B frag

__device__ __forceinline__ float bf2f(u16 v) {
  u32 u = ((u32)v) << 16;
  return __builtin_bit_cast(float, u);
}
__device__ __forceinline__ u16 f2bf(float f) {   // round-to-nearest-even
  u32 x = __builtin_bit_cast(u32, f);
  x += 0x7fffu + ((x >> 16) & 1u);
  return (u16)(x >> 16);
}

// ---------------- Kernel 0: train_mask encoding detector ----------------
__global__ __launch_bounds__(256) void k_detect(const u32* __restrict__ tm, int* __restrict__ flag)
{
  __shared__ int s;
  if (threadIdx.x == 0) s = 0;
  __syncthreads();
  int local = 0;
  #pragma unroll
  for (int j = 0; j < 16; ++j) {
    if (tm[j * 256 + threadIdx.x] > 1u) local = 1;
  }
  if (local) s = 1;
  __syncthreads();
  if (threadIdx.x == 0) *flag = s;
}

// ---------------- Kernel 0b: pre-convert W=[fc1_w;xenc_w] to bf16, K-chunked ----------------
// wws[c*10240 + r*32 + s*8 + j] = bf16(W[r][c*32+s*8+j]), zero-padded past K=500.
// Each wave's MFMA B-fragment is a contiguous 16B load:
//   frag(n,kc) for lane (l15,lgrp) = wws + kc*10240 + (wcol*80+n*16+l15)*32 + lgrp*8.
__global__ __launch_bounds__(256) void k_cvtw(
    const float* __restrict__ fc1w, const float* __restrict__ xencw, u16* __restrict__ wws)
{
  const int g = blockIdx.x * 256 + threadIdx.x;   // 20480 groups
  const int c = g / 1280;
  const int rem = g - c * 1280;
  const int r = rem >> 2;
  const int k0 = c * 32 + (rem & 3) * 8;
  const float* src = (r < H_DIM) ? (fc1w + (long)r * F_DIM)
                                 : (xencw + (long)(r - H_DIM) * F_DIM);
  f32x4 v0 = {0.f, 0.f, 0.f, 0.f}, v1 = v0;
  if (k0 + 4 <= F_DIM) v0 = *(const f32x4*)(src + k0);
  if (k0 + 8 <= F_DIM) v1 = *(const f32x4*)(src + k0 + 4);
  u16x8 o;
  #pragma unroll
  for (int i = 0; i < 4; ++i) { o[i] = f2bf(v0[i]); o[4 + i] = f2bf(v1[i]); }
  *(u16x8*)(wws + (size_t)g * 8) = o;
}

// ---------------- Kernel 1: [h|xe] = relu(x @ W^T + b) ----------------
// v5 (occupancy build): 512 thr = 8 waves (wr=wid>>2 row-half, wcol=wid&3 col-strip);
// per-wave acc[2][5] = 40 AGPR -> total regs ~115 -> 4 waves/SIMD (16 waves/CU).
// ALL 16 K-chunks bulk-staged once (64 KB LDS, 2 blocks/CU) -> barrier-free K-loop.
// B: global->reg->MFMA, 1-step double buffer (L2-resident wws).
#define G_BM 64
#define G_BK 32
#define BN   320

__global__ __launch_bounds__(512, 4) void k_gemm1(
    const float* __restrict__ x, const u16* __restrict__ wws,
    const float* __restrict__ fc1b, const float* __restrict__ xencb,
    u16* __restrict__ hout)
{
  __shared__ u16 sAl[32768];                // 16 chunks x 64 rows x 32 u16 = 64 KB
  u16* sOut = sAl;                          // epilogue alias: 64 x 328 u16 = 42 KB

  const int tid  = threadIdx.x;
  const int lane = tid & 63;
  const int wid  = tid >> 6;
  const int wr   = wid >> 2;                // row half (0..1)
  const int wcol = wid & 3;                 // col strip (0..3)
  const int l15 = lane & 15, lgrp = lane >> 4;
  const long rowbase = (long)blockIdx.x * G_BM;

  // A staging: thread t -> row ar=t>>3, f32x4 slot as=t&7 (8 x 4 f32 = K-chunk row)
  const int ar   = tid >> 3;
  const int as   = tid & 7;
  const int glog = as >> 1, half = as & 1;
  const int gph  = glog ^ ((ar >> 1) & 3);  // validated 16B-group XOR swizzle
  const long arow = rowbase + ar;
  const bool arv = (arow < N_NODES);
  const float* xrow = x + arow * F_DIM;

  const int rslot = (lgrp ^ ((l15 >> 1) & 3)) * 8;   // read-side swizzle ((row>>1)&3 == (l15>>1)&3)

  // ---- bulk stage: all 16 chunks, one barrier ----
  #pragma unroll 4
  for (int c = 0; c < 16; ++c) {
    const int k0 = c * G_BK + as * 4;
    f32x4 v = {0.f, 0.f, 0.f, 0.f};
    if (arv && k0 + 4 <= F_DIM) v = *(const f32x4*)(xrow + k0);
    u16x4 o;
    #pragma unroll
    for (int i = 0; i < 4; ++i) o[i] = f2bf(v[i]);
    *(u16x4*)(sAl + c * 2048 + ar * 32 + gph * 8 + half * 4) = o;
  }

  f32x4 acc[2][5];
  #pragma unroll
  for (int m = 0; m < 2; ++m)
    #pragma unroll
    for (int n = 0; n < 5; ++n)
      acc[m][n] = (f32x4){0.f, 0.f, 0.f, 0.f};

  // B fragment base (rows fixed across K)
  const u16* bbase = wws + (wcol * 80 + l15) * 32 + lgrp * 8;

#define LOAD_B(dst, kc)                                                        \
  {                                                                            \
    const u16* bp = bbase + (size_t)(kc) * (BN * G_BK);                        \
    _Pragma("unroll")                                                          \
    for (int n = 0; n < 5; ++n) dst[n] = *(const bf16x8*)(bp + n * 512);       \
  }

#define GSTEP(kc, BU, BL)                                                      \
  {                                                                            \
    if ((kc) < 15) LOAD_B(BL, (kc) + 1);                                       \
    const u16* sa = sAl + (kc) * 2048 + (wr * 32 + l15) * 32 + rslot;          \
    _Pragma("unroll")                                                          \
    for (int m = 0; m < 2; ++m) {                                              \
      const bf16x8 afr = *(const bf16x8*)(sa + m * 512);                       \
      _Pragma("unroll")                                                        \
      for (int n = 0; n < 5; ++n)                                              \
        acc[m][n] = __builtin_amdgcn_mfma_f32_16x16x32_bf16(afr, BU[n], acc[m][n], 0, 0, 0); \
    }                                                                          \
  }

  bf16x8 bA[5], bB[5];
  LOAD_B(bA, 0);                 // in flight across the staging burst
  __syncthreads();               // A tile ready

  GSTEP(0,  bA, bB); GSTEP(1,  bB, bA); GSTEP(2,  bA, bB); GSTEP(3,  bB, bA);
  GSTEP(4,  bA, bB); GSTEP(5,  bB, bA); GSTEP(6,  bA, bB); GSTEP(7,  bB, bA);
  GSTEP(8,  bA, bB); GSTEP(9,  bB, bA); GSTEP(10, bA, bB); GSTEP(11, bB, bA);
  GSTEP(12, bA, bB); GSTEP(13, bB, bA); GSTEP(14, bA, bB); GSTEP(15, bB, bA);

  __syncthreads();               // sAl dead; alias as sOut

  // ---- epilogue: bias+relu -> LDS (stride 328) -> coalesced 16B stores ----
  // C/D: col=l15, row=lgrp*4+rg within frag; wave rows = wr*32 + m*16.
  #pragma unroll
  for (int n = 0; n < 5; ++n) {
    const int col = wcol * 80 + n * 16 + l15;
    const float bias = (col < H_DIM) ? fc1b[col] : xencb[col - H_DIM];
    #pragma unroll
    for (int m = 0; m < 2; ++m) {
      const int r0 = wr * 32 + m * 16 + lgrp * 4;
      #pragma unroll
      for (int rg = 0; rg < 4; ++rg)
        sOut[(r0 + rg) * 328 + col] = f2bf(fmaxf(acc[m][n][rg] + bias, 0.f));
    }
  }
  __syncthreads();
  #pragma unroll
  for (int it = 0; it < 5; ++it) {
    const int g = it * 512 + tid;            // 2560 groups: 64 rows x 40
    const int r = g / 40, c2 = g - r * 40;
    const long rr = rowbase + r;
    if (rr < N_NODES)
      *(u16x8*)(hout + rr * O_DIM + c2 * 8) = *(const u16x8*)(sOut + r * 328 + c2 * 8);
  }
#undef LOAD_B
#undef GSTEP
}

// ---------------- Kernel 2: MFMA row head (validated round 4) ----------------
#define RH_BM 32
#define RH_LD 328

__global__ __launch_bounds__(128) void k_rowhead(
    const u16* __restrict__ hws, const int* __restrict__ y, const void* __restrict__ tmask,
    const float* __restrict__ fc2w, const float* __restrict__ fc2b, const float* __restrict__ pw,
    const int* __restrict__ mask_flag,
    float* __restrict__ out_lp, float* __restrict__ sq_out, float* __restrict__ sk_out)
{
  __shared__ u16 sA[RH_BM * RH_LD];
  __shared__ u16 sB[48 * RH_LD];
  const int tid = threadIdx.x;
  const int lane = tid & 63, wid = tid >> 6;
  const int l15 = lane & 15, lgrp = lane >> 4;
  const long rowbase = (long)blockIdx.x * RH_BM;

  #pragma unroll
  for (int it = 0; it < 10; ++it) {
    const int g = it * 128 + tid;
    const int r = g / 40, c = g - r * 40;
    *(u16x8*)&sA[r * RH_LD + c * 8] =
        *(const u16x8*)(hws + (rowbase + r) * O_DIM + c * 8);
  }
  #pragma unroll
  for (int it = 0; it < 15; ++it) {
    const int g = it * 128 + tid;
    const int r = g / 40, c = g - r * 40;
    const int k0 = c * 8;
    u16x8 v = {0, 0, 0, 0, 0, 0, 0, 0};
    const float* src = nullptr;
    if (r < C_DIM) { if (k0 < H_DIM) src = fc2w + r * H_DIM + k0; }
    else if (r == C_DIM)     { if (k0 >= H_DIM) src = pw + (k0 - H_DIM); }
    else if (r == C_DIM + 1) { if (k0 >= H_DIM) src = pw + HX_DIM + (k0 - H_DIM); }
    if (src) {
      const f32x4 v0 = *(const f32x4*)src;
      const f32x4 v1 = *(const f32x4*)(src + 4);
      #pragma unroll
      for (int i = 0; i < 4; ++i) { v[i] = f2bf(v0[i]); v[4 + i] = f2bf(v1[i]); }
    }
    *(u16x8*)&sB[r * RH_LD + c * 8] = v;
  }
  __syncthreads();

  f32x4 acc[3];
  #pragma unroll
  for (int n = 0; n < 3; ++n) acc[n] = (f32x4){0.f, 0.f, 0.f, 0.f};
  const u16* pa = &sA[(wid * 16 + l15) * RH_LD + lgrp * 8];
  const u16* pb = &sB[l15 * RH_LD + lgrp * 8];
  #pragma unroll
  for (int kc = 0; kc < 10; ++kc) {
    const bf16x8 a = *(const bf16x8*)(pa + kc * 32);
    #pragma unroll
    for (int n = 0; n < 3; ++n) {
      const bf16x8 b = *(const bf16x8*)(pb + n * 16 * RH_LD + kc * 32);
      acc[n] = __builtin_amdgcn_mfma_f32_16x16x32_bf16(a, b, acc[n], 0, 0, 0);
    }
  }

  const int c0 = l15, c1 = 16 + l15, c2 = 32 + l15;
  const bool v2 = (l15 < 8);
  const float b0 = fc2b[c0], b1 = fc2b[c1], b2 = v2 ? fc2b[c2] : 0.f;
  const float wq0 = pw[2 * HX_DIM + c0], wq1 = pw[2 * HX_DIM + c1],
              wq2 = v2 ? pw[2 * HX_DIM + c2] : 0.f;
  const float wk0 = pw[2 * HX_DIM + C_DIM + c0], wk1 = pw[2 * HX_DIM + C_DIM + c1],
              wk2 = v2 ? pw[2 * HX_DIM + C_DIM + c2] : 0.f;
  const bool byte_mask = (*mask_flag != 0);

  #pragma unroll
  for (int rg = 0; rg < 4; ++rg) {
    const long row = rowbase + wid * 16 + lgrp * 4 + rg;
    const float lg0 = acc[0][rg] + b0;
    const float lg1 = acc[1][rg] + b1;
    const float lg2 = acc[2][rg] + b2;
    const float sxq = __shfl(acc[2][rg], (lane & 48) | 8, 64);
    const float sxk = __shfl(acc[2][rg], (lane & 48) | 9, 64);

    float m = fmaxf(lg0, lg1);
    if (v2) m = fmaxf(m, lg2);
    #pragma unroll
    for (int off = 1; off < 16; off <<= 1) m = fmaxf(m, __shfl_xor(m, off, 64));
    const float e0 = __expf(lg0 - m), e1 = __expf(lg1 - m),
                e2 = v2 ? __expf(lg2 - m) : 0.f;
    float s = e0 + e1 + e2;
    #pragma unroll
    for (int off = 1; off < 16; off <<= 1) s += __shfl_xor(s, off, 64);
    const float lse = m + __logf(s);
    const float inv = 1.f / s;

    const int yv = y[row];
    const bool tm = byte_mask ? (((const unsigned char*)tmask)[row] != 0)
                              : (((const int*)tmask)[row] != 0);
    const float p0 = tm ? (c0 == yv ? 1.f : 0.f) : e0 * inv;
    const float p1 = tm ? (c1 == yv ? 1.f : 0.f) : e1 * inv;
    const float p2 = tm ? (c2 == yv ? 1.f : 0.f) : e2 * inv;
    float sq = p0 * wq0 + p1 * wq1 + p2 * wq2;
    float sk = p0 * wk0 + p1 * wk1 + p2 * wk2;
    #pragma unroll
    for (int off = 1; off < 16; off <<= 1) {
      sq += __shfl_xor(sq, off, 64);
      sk += __shfl_xor(sk, off, 64);
    }

    float* lp = out_lp + row * C_DIM;
    lp[c0] = lg0 - lse;
    lp[c1] = lg1 - lse;
    if (v2) lp[c2] = lg2 - lse;
    if (l15 == 0) { sq_out[row] = sq + sxq; sk_out[row] = sk + sxk; }
  }
}

// ---------------- Kernel 3: edge scores ----------------
__global__ __launch_bounds__(256) void k_edges(
    const int* __restrict__ ei, const int* __restrict__ ein,
    const float* __restrict__ sq, const float* __restrict__ sk,
    const float* __restrict__ pb, float* __restrict__ out)
{
  const int e = blockIdx.x * 256 + threadIdx.x;
  if (e >= E_NUM) return;
  const float b = pb[0];
  const int a0 = ei[e],  a1 = ei[E_NUM + e];
  out[e] = sq[a0] + sk[a1] + b;
  const int c0 = ein[e], c1 = ein[E_NUM + e];
  out[E_NUM + e] = sq[c0] + sk[c1] + b;
}

extern "C" void kernel_launch(void* const* d_in, const int* in_sizes, int n_in,
                              void* d_out, int out_size, void* d_ws, size_t ws_size,
                              hipStream_t stream)
{
  const float* x     = (const float*)d_in[0];
  const int*   y     = (const int*)d_in[1];
  const void*  tm    = d_in[2];
  const int*   ei    = (const int*)d_in[3];
  const int*   ein   = (const int*)d_in[4];
  const float* fc1w  = (const float*)d_in[5];
  const float* fc1b  = (const float*)d_in[6];
  const float* fc2w  = (const float*)d_in[7];
  const float* fc2b  = (const float*)d_in[8];
  const float* xencw = (const float*)d_in[9];
  const float* xencb = (const float*)d_in[10];
  const float* pw    = (const float*)d_in[11];
  const float* pb    = (const float*)d_in[12];
  float* out = (float*)d_out;

  // ws: hws (N*320 bf16 = 64 MB) | s_q | s_k | flag | wws (320 KB)
  u16*   hws  = (u16*)d_ws;
  float* sq   = (float*)((char*)d_ws + (size_t)N_NODES * O_DIM * 2);
  float* sk   = sq + N_NODES;
  int*   flag = (int*)(sk + N_NODES);
  u16*   wws  = (u16*)((char*)d_ws + 64800064);

  k_detect<<<1, 256, 0, stream>>>((const u32*)tm, flag);
  k_cvtw  <<<80, 256, 0, stream>>>(fc1w, xencw, wws);
  const int nrb = (N_NODES + G_BM - 1) / G_BM;    // 1563
  k_gemm1 <<<nrb, 512, 0, stream>>>(x, wws, fc1b, xencb, hws);
  k_rowhead<<<N_NODES / RH_BM, 128, 0, stream>>>(
      hws, y, tm, fc2w, fc2b, pw, flag, out + 2 * (size_t)E_NUM, sq, sk);
  k_edges <<<E_NUM / 256, 256, 0, stream>>>(ei, ein, sq, sk, pb, out);
}

// Round 9
// 140.452 us; speedup vs baseline: 1.4974x; 1.4974x over previous
//
#include <hip/hip_runtime.h>
#include <stdint.h>

#define N_NODES 100000
#define F_DIM   500
#define C_DIM   40
#define H_DIM   256
#define HX_DIM  64
#define O_DIM   320   // H + HX
#define E_NUM   1600000

typedef unsigned short u16;
typedef unsigned int   u32;
typedef __attribute__((ext_vector_type(4))) u16    u16x4;
typedef __attribute__((ext_vector_type(8))) u16    u16x8;
typedef __attribute__((ext_vector_type(4))) float  f32x4;
typedef __attribute__((ext_vector_type(8))) short  bf16x8;  // MFMA A/B frag

__device__ __forceinline__ float bf2f(u16 v) {
  u32 u = ((u32)v) << 16;
  return __builtin_bit_cast(float, u);
}
__device__ __forceinline__ u16 f2bf(float f) {   // round-to-nearest-even
  u32 x = __builtin_bit_cast(u32, f);
  x += 0x7fffu + ((x >> 16) & 1u);
  return (u16)(x >> 16);
}

// ---------------- Kernel 0: train_mask encoding detector ----------------
__global__ __launch_bounds__(256) void k_detect(const u32* __restrict__ tm, int* __restrict__ flag)
{
  __shared__ int s;
  if (threadIdx.x == 0) s = 0;
  __syncthreads();
  int local = 0;
  #pragma unroll
  for (int j = 0; j < 16; ++j) {
    if (tm[j * 256 + threadIdx.x] > 1u) local = 1;
  }
  if (local) s = 1;
  __syncthreads();
  if (threadIdx.x == 0) *flag = s;
}

// ---------------- Kernel 0b: pre-convert W=[fc1_w;xenc_w] to bf16, K-chunked ----------------
// wws[c*10240 + r*32 + s*8 + j] = bf16(W[r][c*32+s*8+j]), zero-padded past K=500.
__global__ __launch_bounds__(256) void k_cvtw(
    const float* __restrict__ fc1w, const float* __restrict__ xencw, u16* __restrict__ wws)
{
  const int g = blockIdx.x * 256 + threadIdx.x;   // 20480 groups
  const int c = g / 1280;
  const int rem = g - c * 1280;
  const int r = rem >> 2;
  const int k0 = c * 32 + (rem & 3) * 8;
  const float* src = (r < H_DIM) ? (fc1w + (long)r * F_DIM)
                                 : (xencw + (long)(r - H_DIM) * F_DIM);
  f32x4 v0 = {0.f, 0.f, 0.f, 0.f}, v1 = v0;
  if (k0 + 4 <= F_DIM) v0 = *(const f32x4*)(src + k0);
  if (k0 + 8 <= F_DIM) v1 = *(const f32x4*)(src + k0 + 4);
  u16x8 o;
  #pragma unroll
  for (int i = 0; i < 4; ++i) { o[i] = f2bf(v0[i]); o[4 + i] = f2bf(v1[i]); }
  *(u16x8*)(wws + (size_t)g * 8) = o;
}

// ---------------- Kernel 1: FUSED  [h|xe] = relu(x W^T + b)  ->  logits/softmax/s_q/s_k ----------------
// Phase 1 (GEMM): BM=64 x BN=320, BK=32, 512 thr (8 waves = 2 row x 4 col), K-tile
//   bulk-staged in LDS (64 KB), B global->reg->MFMA with 2-DEEP prefetch (3 buffers).
// Phase 2: h|xe tile lands in LDS (stride 328, == validated rowhead layout); B' (48x320)
//   staged; waves 0-3 run the validated rowhead MFMA + softmax + s_q/s_k in-block.
// hws NEVER touches global memory (-128 MB round-trip vs r8).
#define G_BM 64
#define G_BK 32
#define BN   320
#define RH_LD 328

__global__ __launch_bounds__(512, 4) void k_fused(
    const float* __restrict__ x, const u16* __restrict__ wws,
    const float* __restrict__ fc1b, const float* __restrict__ xencb,
    const int* __restrict__ y, const void* __restrict__ tmask,
    const float* __restrict__ fc2w, const float* __restrict__ fc2b,
    const float* __restrict__ pw, const int* __restrict__ mask_flag,
    float* __restrict__ out_lp, float* __restrict__ sq_out, float* __restrict__ sk_out)
{
  // LDS: phase1 sAl = 16 chunks x 2048 u16 = 64 KB; phase2 alias:
  //   sOut 64x328 u16 (42 KB) | sBp 48x328 u16 (31.5 KB)  => 73472 B total, 2 blocks/CU.
  __shared__ __align__(16) u16 smem[36736];
  u16* sAl  = smem;
  u16* sOut = smem;            // [64][328]
  u16* sBp  = smem + 20992;    // [48][328]

  const int tid  = threadIdx.x;
  const int lane = tid & 63;
  const int wid  = tid >> 6;
  const int wr   = wid >> 2;                // row half (0..1)
  const int wcol = wid & 3;                 // col strip (0..3)
  const int l15 = lane & 15, lgrp = lane >> 4;
  const long rowbase = (long)blockIdx.x * G_BM;

  // A staging geometry: thread t -> row ar=t>>3, f32x4 slot as=t&7
  const int ar   = tid >> 3;
  const int as   = tid & 7;
  const int glog = as >> 1, half = as & 1;
  const int gph  = glog ^ ((ar >> 1) & 3);  // validated 16B-group XOR swizzle
  const long arow = rowbase + ar;
  const bool arv = (arow < N_NODES);
  const float* xrow = x + arow * F_DIM;
  const int rslot = (lgrp ^ ((l15 >> 1) & 3)) * 8;   // read-side swizzle

  // B fragment base (rows fixed across K)
  const u16* bbase = wws + (wcol * 80 + l15) * 32 + lgrp * 8;

#define LOAD_B(dst, kc)                                                        \
  {                                                                            \
    const u16* bp = bbase + (size_t)(kc) * (BN * G_BK);                        \
    _Pragma("unroll")                                                          \
    for (int n = 0; n < 5; ++n) dst[n] = *(const bf16x8*)(bp + n * 512);       \
  }

  bf16x8 bX[5], bY[5], bZ[5];
  LOAD_B(bX, 0);
  LOAD_B(bY, 1);

  // ---- staging: two 8-deep load batches (2 latency exposures) ----
  f32x4 xr[8];
  #pragma unroll
  for (int c = 0; c < 8; ++c) {            // k0 <= 252+4 <= 500: always in-bounds
    xr[c] = (f32x4){0.f, 0.f, 0.f, 0.f};
    if (arv) xr[c] = *(const f32x4*)(xrow + c * 32 + as * 4);
  }
  #pragma unroll
  for (int c = 0; c < 8; ++c) {
    u16x4 o;
    #pragma unroll
    for (int i = 0; i < 4; ++i) o[i] = f2bf(xr[c][i]);
    *(u16x4*)(sAl + c * 2048 + ar * 32 + gph * 8 + half * 4) = o;
  }
  #pragma unroll
  for (int c = 8; c < 16; ++c) {
    const int k0 = c * 32 + as * 4;
    xr[c - 8] = (f32x4){0.f, 0.f, 0.f, 0.f};
    if (arv && k0 + 4 <= F_DIM) xr[c - 8] = *(const f32x4*)(xrow + k0);
  }
  #pragma unroll
  for (int c = 8; c < 16; ++c) {
    u16x4 o;
    #pragma unroll
    for (int i = 0; i < 4; ++i) o[i] = f2bf(xr[c - 8][i]);
    *(u16x4*)(sAl + c * 2048 + ar * 32 + gph * 8 + half * 4) = o;
  }

  f32x4 acc[2][5];
  #pragma unroll
  for (int m = 0; m < 2; ++m)
    #pragma unroll
    for (int n = 0; n < 5; ++n)
      acc[m][n] = (f32x4){0.f, 0.f, 0.f, 0.f};

  __syncthreads();               // A tile ready

#define GS(kc, BU, BL)                                                         \
  {                                                                            \
    if ((kc) + 2 < 16) LOAD_B(BL, (kc) + 2);                                   \
    const u16* sa = sAl + (kc) * 2048 + (wr * 32 + l15) * 32 + rslot;          \
    _Pragma("unroll")                                                          \
    for (int m = 0; m < 2; ++m) {                                              \
      const bf16x8 afr = *(const bf16x8*)(sa + m * 512);                       \
      _Pragma("unroll")                                                        \
      for (int n = 0; n < 5; ++n)                                              \
        acc[m][n] = __builtin_amdgcn_mfma_f32_16x16x32_bf16(afr, BU[n], acc[m][n], 0, 0, 0); \
    }                                                                          \
  }

  GS(0,  bX, bZ)  GS(1,  bY, bX)  GS(2,  bZ, bY)  GS(3,  bX, bZ)
  GS(4,  bY, bX)  GS(5,  bZ, bY)  GS(6,  bX, bZ)  GS(7,  bY, bX)
  GS(8,  bZ, bY)  GS(9,  bX, bZ)  GS(10, bY, bX)  GS(11, bZ, bY)
  GS(12, bX, bZ)  GS(13, bY, bX)  GS(14, bZ, bY)  GS(15, bX, bY)

  __syncthreads();               // sAl dead; alias as sOut/sBp

  // ---- write h|xe tile to LDS (validated rowhead layout) + stage B' ----
  #pragma unroll
  for (int n = 0; n < 5; ++n) {
    const int col = wcol * 80 + n * 16 + l15;
    const float bias = (col < H_DIM) ? fc1b[col] : xencb[col - H_DIM];
    #pragma unroll
    for (int m = 0; m < 2; ++m) {
      const int r0 = wr * 32 + m * 16 + lgrp * 4;
      #pragma unroll
      for (int rg = 0; rg < 4; ++rg)
        sOut[(r0 + rg) * RH_LD + col] = f2bf(fmaxf(acc[m][n][rg] + bias, 0.f));
    }
  }
  // B' rows 0-39 [fc2w | 0], 40 [0|w_xq], 41 [0|w_xk], 42-47 zero (48 x 40 groups)
  #pragma unroll
  for (int it = 0; it < 4; ++it) {
    const int g = it * 512 + tid;
    if (g < 1920) {
      const int r = g / 40, c = g - r * 40;
      const int k0 = c * 8;
      u16x8 v = {0, 0, 0, 0, 0, 0, 0, 0};
      const float* src = nullptr;
      if (r < C_DIM) { if (k0 < H_DIM) src = fc2w + r * H_DIM + k0; }
      else if (r == C_DIM)     { if (k0 >= H_DIM) src = pw + (k0 - H_DIM); }
      else if (r == C_DIM + 1) { if (k0 >= H_DIM) src = pw + HX_DIM + (k0 - H_DIM); }
      if (src) {
        const f32x4 v0 = *(const f32x4*)src;
        const f32x4 v1 = *(const f32x4*)(src + 4);
        #pragma unroll
        for (int i = 0; i < 4; ++i) { v[i] = f2bf(v0[i]); v[4 + i] = f2bf(v1[i]); }
      }
      *(u16x8*)&sBp[r * RH_LD + c * 8] = v;
    }
  }
  __syncthreads();

  // ---- rowhead (waves 0-3; 16 rows each) — validated round-4/5 math ----
  if (wid < 4) {
    f32x4 racc[3];
    #pragma unroll
    for (int n = 0; n < 3; ++n) racc[n] = (f32x4){0.f, 0.f, 0.f, 0.f};
    const u16* pa = &sOut[(wid * 16 + l15) * RH_LD + lgrp * 8];
    const u16* pb = &sBp[l15 * RH_LD + lgrp * 8];
    #pragma unroll
    for (int kc = 0; kc < 10; ++kc) {
      const bf16x8 a = *(const bf16x8*)(pa + kc * 32);
      #pragma unroll
      for (int n = 0; n < 3; ++n) {
        const bf16x8 b = *(const bf16x8*)(pb + n * 16 * RH_LD + kc * 32);
        racc[n] = __builtin_amdgcn_mfma_f32_16x16x32_bf16(a, b, racc[n], 0, 0, 0);
      }
    }

    const int c0 = l15, c1 = 16 + l15, c2 = 32 + l15;
    const bool v2 = (l15 < 8);
    const float b0 = fc2b[c0], b1 = fc2b[c1], b2 = v2 ? fc2b[c2] : 0.f;
    const float wq0 = pw[2 * HX_DIM + c0], wq1 = pw[2 * HX_DIM + c1],
                wq2 = v2 ? pw[2 * HX_DIM + c2] : 0.f;
    const float wk0 = pw[2 * HX_DIM + C_DIM + c0], wk1 = pw[2 * HX_DIM + C_DIM + c1],
                wk2 = v2 ? pw[2 * HX_DIM + C_DIM + c2] : 0.f;
    const bool byte_mask = (*mask_flag != 0);

    #pragma unroll
    for (int rg = 0; rg < 4; ++rg) {
      const long row = rowbase + wid * 16 + lgrp * 4 + rg;
      const bool rv = (row < N_NODES);
      const long rowc = rv ? row : (N_NODES - 1);
      const float lg0 = racc[0][rg] + b0;
      const float lg1 = racc[1][rg] + b1;
      const float lg2 = racc[2][rg] + b2;
      const float sxq = __shfl(racc[2][rg], (lane & 48) | 8, 64);   // col 40: xe.w_xq
      const float sxk = __shfl(racc[2][rg], (lane & 48) | 9, 64);   // col 41: xe.w_xk

      float m = fmaxf(lg0, lg1);
      if (v2) m = fmaxf(m, lg2);
      #pragma unroll
      for (int off = 1; off < 16; off <<= 1) m = fmaxf(m, __shfl_xor(m, off, 64));
      const float e0 = __expf(lg0 - m), e1 = __expf(lg1 - m),
                  e2 = v2 ? __expf(lg2 - m) : 0.f;
      float s = e0 + e1 + e2;
      #pragma unroll
      for (int off = 1; off < 16; off <<= 1) s += __shfl_xor(s, off, 64);
      const float lse = m + __logf(s);
      const float inv = 1.f / s;

      const int yv = y[rowc];
      const bool tm = byte_mask ? (((const unsigned char*)tmask)[rowc] != 0)
                                : (((const int*)tmask)[rowc] != 0);
      const float p0 = tm ? (c0 == yv ? 1.f : 0.f) : e0 * inv;
      const float p1 = tm ? (c1 == yv ? 1.f : 0.f) : e1 * inv;
      const float p2 = tm ? (c2 == yv ? 1.f : 0.f) : e2 * inv;
      float sq = p0 * wq0 + p1 * wq1 + p2 * wq2;
      float sk = p0 * wk0 + p1 * wk1 + p2 * wk2;
      #pragma unroll
      for (int off = 1; off < 16; off <<= 1) {
        sq += __shfl_xor(sq, off, 64);
        sk += __shfl_xor(sk, off, 64);
      }

      if (rv) {
        float* lp = out_lp + row * C_DIM;
        lp[c0] = lg0 - lse;
        lp[c1] = lg1 - lse;
        if (v2) lp[c2] = lg2 - lse;
        if (l15 == 0) { sq_out[row] = sq + sxq; sk_out[row] = sk + sxk; }
      }
    }
  }
#undef LOAD_B
#undef GS
}

// ---------------- Kernel 3: edge scores ----------------
__global__ __launch_bounds__(256) void k_edges(
    const int* __restrict__ ei, const int* __restrict__ ein,
    const float* __restrict__ sq, const float* __restrict__ sk,
    const float* __restrict__ pb, float* __restrict__ out)
{
  const int e = blockIdx.x * 256 + threadIdx.x;
  if (e >= E_NUM) return;
  const float b = pb[0];
  const int a0 = ei[e],  a1 = ei[E_NUM + e];
  out[e] = sq[a0] + sk[a1] + b;
  const int c0 = ein[e], c1 = ein[E_NUM + e];
  out[E_NUM + e] = sq[c0] + sk[c1] + b;
}

extern "C" void kernel_launch(void* const* d_in, const int* in_sizes, int n_in,
                              void* d_out, int out_size, void* d_ws, size_t ws_size,
                              hipStream_t stream)
{
  const float* x     = (const float*)d_in[0];
  const int*   y     = (const int*)d_in[1];
  const void*  tm    = d_in[2];
  const int*   ei    = (const int*)d_in[3];
  const int*   ein   = (const int*)d_in[4];
  const float* fc1w  = (const float*)d_in[5];
  const float* fc1b  = (const float*)d_in[6];
  const float* fc2w  = (const float*)d_in[7];
  const float* fc2b  = (const float*)d_in[8];
  const float* xencw = (const float*)d_in[9];
  const float* xencb = (const float*)d_in[10];
  const float* pw    = (const float*)d_in[11];
  const float* pb    = (const float*)d_in[12];
  float* out = (float*)d_out;

  // ws layout unchanged (hws region now unused): | s_q | s_k | flag | wws (320 KB)
  float* sq   = (float*)((char*)d_ws + (size_t)N_NODES * O_DIM * 2);
  float* sk   = sq + N_NODES;
  int*   flag = (int*)(sk + N_NODES);
  u16*   wws  = (u16*)((char*)d_ws + 64800064);

  k_detect<<<1, 256, 0, stream>>>((const u32*)tm, flag);
  k_cvtw  <<<80, 256, 0, stream>>>(fc1w, xencw, wws);
  const int nrb = (N_NODES + G_BM - 1) / G_BM;    // 1563
  k_fused <<<nrb, 512, 0, stream>>>(x, wws, fc1b, xencb, y, tm, fc2w, fc2b, pw, flag,
                                    out + 2 * (size_t)E_NUM, sq, sk);
  k_edges <<<E_NUM / 256, 256, 0, stream>>>(ei, ein, sq, sk, pb, out);
}